// Round 6
// baseline (275.331 us; speedup 1.0000x reference)
//
#include <hip/hip_runtime.h>
#include <math.h>

// Cached SDPA decode: B=8 H=32 Q=1 D=128, MAX_SEQ=4096, fp32 in/out.
// R6: R4 two-phase structure (2048 blocks x 4 waves = 32 waves/CU, proven
// 6.19 TB/s stream) but with the combine fused as an atomic finisher:
// each (bh,split) block writes its partial, releases via __threadfence,
// atomicAdd's a per-bh counter; the 8th arriver acquires and combines
// inline (fixed p=0..7 order -> deterministic, bit-identical to R4).
// Counters zeroed by a 1KB hipMemsetAsync prologue each call.

#define BH_     256                  // B*H
#define D_      128
#define MAXS_   4096
#define NSPLIT_ 8
#define CHUNK_  (MAXS_ / NSPLIT_)    // 512 keys per block
#define NWAVES_ 4
#define KPW_    (CHUNK_ / NWAVES_)   // 128 keys per wave
#define NPART_  (NWAVES_ * 2)        // 8 half-wave partials per block
#define PSTRIDE_ (D_ + 2)            // o[128], m, l
#define PART_BYTES_ ((size_t)BH_ * NSPLIT_ * PSTRIDE_ * 4)  // 1,064,960 B

typedef float f4n __attribute__((ext_vector_type(4)));

static __device__ __forceinline__ f4n ntld4(const float* p) {
    return __builtin_nontemporal_load((const f4n*)p);
}

__global__ __launch_bounds__(256, 8) void attn_partial_fused_kernel(
    const float* __restrict__ q,
    const float* __restrict__ knew,
    const float* __restrict__ vnew,
    const float* __restrict__ ck,
    const float* __restrict__ cv,
    const int*   __restrict__ cpos_p,
    float*       __restrict__ part,
    unsigned int* __restrict__ ctr,
    float*       __restrict__ out)
{
    const int bh    = blockIdx.x;        // 0..255
    const int split = blockIdx.y;        // 0..7
    const int wave  = threadIdx.x >> 6;  // 0..3
    const int lane  = threadIdx.x & 63;
    const int half  = lane >> 5;         // which of the 2 keys/iter
    const int li    = lane & 31;         // dim-group owner within half

    const int cpos = cpos_p[0];          // hot loop covers cache rows [0,cpos)

    const float scale = 0.08838834764831845f;  // 1/sqrt(128)

    // lane owns dims 4*li..4*li+3 (same dims in both halves); scale folded in
    f4n qv = *(const f4n*)(q + (size_t)bh * D_ + li * 4);
    qv *= scale;

    const int base  = split * CHUNK_ + wave * KPW_;
    int limit = cpos - base;
    limit = limit < 0 ? 0 : (limit > KPW_ ? KPW_ : limit);

    float m = -INFINITY;
    float l = 0.0f;
    f4n   o = {0.0f, 0.0f, 0.0f, 0.0f};

    const float* __restrict__ kbase = ck + (size_t)bh * MAXS_ * D_;
    const float* __restrict__ vbase = cv + (size_t)bh * MAXS_ * D_;

#define UPDATE(KV, VV)                                                   \
    do {                                                                 \
        float dp = (KV).x * qv.x + (KV).y * qv.y                         \
                 + (KV).z * qv.z + (KV).w * qv.w;                        \
        dp += __shfl_xor(dp, 16);                                        \
        dp += __shfl_xor(dp, 8);                                         \
        dp += __shfl_xor(dp, 4);                                         \
        dp += __shfl_xor(dp, 2);                                         \
        dp += __shfl_xor(dp, 1);                                         \
        const float mn   = fmaxf(m, dp);                                 \
        const float corr = __expf(m - mn);                               \
        const float p    = __expf(dp - mn);                              \
        l   = l   * corr + p;                                            \
        o.x = o.x * corr + p * (VV).x;                                   \
        o.y = o.y * corr + p * (VV).y;                                   \
        o.z = o.z * corr + p * (VV).z;                                   \
        o.w = o.w * corr + p * (VV).w;                                   \
        m = mn;                                                          \
    } while (0)

    if (limit == KPW_) {
        // fast path: full 128-key tile, 2-stage pipeline (2 wave-loads ahead)
        const float* kp = kbase + (size_t)base * D_ + lane * 4;
        const float* vp = vbase + (size_t)base * D_ + lane * 4;
        f4n ka = ntld4(kp),        va = ntld4(vp);
        f4n kb = ntld4(kp + 256),  vb = ntld4(vp + 256);
        kp += 512; vp += 512;
        for (int i = 0; i < (KPW_ / 4) - 1; ++i) {   // 31 iterations
            const f4n kc = ntld4(kp),       vc = ntld4(vp);
            const f4n kd = ntld4(kp + 256), vd = ntld4(vp + 256);
            kp += 512; vp += 512;
            UPDATE(ka, va);
            UPDATE(kb, vb);
            ka = kc; va = vc; kb = kd; vb = vd;
        }
        UPDATE(ka, va);
        UPDATE(kb, vb);
    } else {
        // generic path: paired loop + odd tail (half 0 only)
        const int npairs = limit >> 1;
        for (int i = 0; i < npairs; ++i) {
            const int s0 = base + i * 2;
            const f4n kv = ntld4(kbase + (size_t)s0 * D_ + lane * 4);
            const f4n vv = ntld4(vbase + (size_t)s0 * D_ + lane * 4);
            UPDATE(kv, vv);
        }
        if ((limit & 1) && half == 0) {
            const int s = base + limit - 1;
            const f4n kv = ntld4(kbase + (size_t)s * D_ + li * 4);
            const f4n vv = ntld4(vbase + (size_t)s * D_ + li * 4);
            UPDATE(kv, vv);
        }
    }
#undef UPDATE

    // combine the 8 half-wave partials via LDS -> one partial per block
    __shared__ float s_o[NPART_][D_];
    __shared__ float s_m[NPART_];
    __shared__ float s_l[NPART_];
    const int pi = wave * 2 + half;
    *(f4n*)&s_o[pi][li * 4] = o;
    if (li == 0) { s_m[pi] = m; s_l[pi] = l; }
    __syncthreads();

    if (wave != 0) return;

    // ---- wave 0: write this block's partial ----
    {
        float M = -INFINITY;
        #pragma unroll
        for (int p = 0; p < NPART_; ++p) M = fmaxf(M, s_m[p]);

        float* pp = part + ((size_t)bh * NSPLIT_ + split) * PSTRIDE_;
        const int d0 = lane * 2;
        if (M == -INFINITY) {
            pp[d0]     = 0.0f;
            pp[d0 + 1] = 0.0f;
            if (lane == 0) { pp[D_] = -INFINITY; pp[D_ + 1] = 0.0f; }
        } else {
            float L = 0.0f, a0 = 0.0f, a1 = 0.0f;
            #pragma unroll
            for (int p = 0; p < NPART_; ++p) {
                const float mp = s_m[p];
                const float w  = (mp == -INFINITY) ? 0.0f : __expf(mp - M);
                L  += w * s_l[p];
                a0 += w * s_o[p][d0];
                a1 += w * s_o[p][d0 + 1];
            }
            pp[d0]     = a0;
            pp[d0 + 1] = a1;
            if (lane == 0) { pp[D_] = M; pp[D_ + 1] = L; }
        }
    }

    // ---- release partial, arrive; 8th arriver combines inline ----
    __threadfence();                       // release (device scope)
    int old = 0;
    if (lane == 0) old = (int)atomicAdd(&ctr[bh], 1u);
    old = __shfl(old, 0);
    if (old != NSPLIT_ - 1) return;

    __threadfence();                       // acquire (device scope)

    // ---- combine (identical arithmetic/order to R4's combine kernel) ----
    const float2 q2 = *(const float2*)(q    + (size_t)bh * D_ + lane * 2);
    const float2 kn = *(const float2*)(knew + (size_t)bh * D_ + lane * 2);
    float dp = q2.x * kn.x + q2.y * kn.y;
    #pragma unroll
    for (int off = 32; off > 0; off >>= 1) dp += __shfl_xor(dp, off);
    const float sc = dp * scale;

    const float* pb = part + (size_t)bh * NSPLIT_ * PSTRIDE_;

    float M = sc;
    #pragma unroll
    for (int p = 0; p < NSPLIT_; ++p) M = fmaxf(M, pb[p * PSTRIDE_ + D_]);

    const int d0 = lane * 2;
    const float2 vn = *(const float2*)(vnew + (size_t)bh * D_ + d0);
    const float wn = __expf(sc - M);       // new-key partial: m=sc, l=1
    float L  = wn;
    float a0 = wn * vn.x;
    float a1 = wn * vn.y;
    #pragma unroll
    for (int p = 0; p < NSPLIT_; ++p) {
        const float mp = pb[p * PSTRIDE_ + D_];
        const float w  = (mp == -INFINITY) ? 0.0f : __expf(mp - M);
        L  += w * pb[p * PSTRIDE_ + D_ + 1];
        a0 += w * pb[p * PSTRIDE_ + d0];
        a1 += w * pb[p * PSTRIDE_ + d0 + 1];
    }
    out[(size_t)bh * D_ + d0]     = a0 / L;
    out[(size_t)bh * D_ + d0 + 1] = a1 / L;
}

extern "C" void kernel_launch(void* const* d_in, const int* in_sizes, int n_in,
                              void* d_out, int out_size, void* d_ws, size_t ws_size,
                              hipStream_t stream) {
    const float* q    = (const float*)d_in[0];
    const float* knew = (const float*)d_in[1];
    const float* vnew = (const float*)d_in[2];
    const float* ck   = (const float*)d_in[3];
    const float* cv   = (const float*)d_in[4];
    const int*   cpos = (const int*)d_in[5];
    float* out  = (float*)d_out;
    float* part = (float*)d_ws;
    unsigned int* ctr = (unsigned int*)((char*)d_ws + PART_BYTES_);

    // zero the 256 per-bh arrival counters (graph-capturable async memset)
    hipMemsetAsync(ctr, 0, BH_ * sizeof(unsigned int), stream);

    dim3 grid(BH_, NSPLIT_);
    attn_partial_fused_kernel<<<grid, 256, 0, stream>>>(
        q, knew, vnew, ck, cv, cpos, part, ctr, out);
}

// Round 7
// 181.582 us; speedup vs baseline: 1.5163x; 1.5163x over previous
//
#include <hip/hip_runtime.h>
#include <math.h>

// Cached SDPA decode: B=8 H=32 Q=1 D=128, MAX_SEQ=4096, fp32 in/out.
// FINAL (R4 revert): flash-decode split-K, two kernels.
// Kernel1: per-(bh,split) online-softmax partials over cache rows [0,cpos);
// 2048 blocks x 4 waves = 32 waves/CU. Two keys per wave-iteration
// (lanes 0-31 = key s0, lanes 32-63 = key s0+1), float4/lane nontemporal
// loads = 16B/lane fully-coalesced 1KB/wave-load, 2-stage software pipeline.
// Kernel2: one wave per bh merges the 8 split partials + the new key/value
// (logical cache row cpos) as a 9th partial.
// R5 (single-block fusion, 16 waves/CU) and R6 (atomic finisher) both
// regressed: this stream is TLP-limited, and per-block device-scope sync /
// register pressure cost more than the ~5us dispatch tail they remove.

#define BH_     256                  // B*H
#define D_      128
#define MAXS_   4096
#define NSPLIT_ 8
#define CHUNK_  (MAXS_ / NSPLIT_)    // 512 keys per block
#define NWAVES_ 4
#define KPW_    (CHUNK_ / NWAVES_)   // 128 keys per wave
#define NPART_  (NWAVES_ * 2)        // 8 half-wave partials per block
#define PSTRIDE_ (D_ + 2)            // o[128], m, l

typedef float f4n __attribute__((ext_vector_type(4)));

static __device__ __forceinline__ f4n ntld4(const float* p) {
    return __builtin_nontemporal_load((const f4n*)p);
}

__global__ __launch_bounds__(256) void attn_partial_kernel(
    const float* __restrict__ q,
    const float* __restrict__ ck,
    const float* __restrict__ cv,
    const int*   __restrict__ cpos_p,
    float*       __restrict__ part)
{
    const int bh    = blockIdx.x;        // 0..255
    const int split = blockIdx.y;        // 0..7
    const int wave  = threadIdx.x >> 6;  // 0..3
    const int lane  = threadIdx.x & 63;
    const int half  = lane >> 5;         // which of the 2 keys/iter
    const int li    = lane & 31;         // dim-group owner within half

    const int cpos = cpos_p[0];          // hot loop covers cache rows [0,cpos)

    const float scale = 0.08838834764831845f;  // 1/sqrt(128)

    // lane owns dims 4*li .. 4*li+3 (same dims in both halves); scale folded in
    f4n qv = *(const f4n*)(q + (size_t)bh * D_ + li * 4);
    qv *= scale;

    const int base  = split * CHUNK_ + wave * KPW_;
    int limit = cpos - base;
    limit = limit < 0 ? 0 : (limit > KPW_ ? KPW_ : limit);

    float m = -INFINITY;
    float l = 0.0f;
    f4n   o = {0.0f, 0.0f, 0.0f, 0.0f};

    const float* __restrict__ kbase = ck + (size_t)bh * MAXS_ * D_;
    const float* __restrict__ vbase = cv + (size_t)bh * MAXS_ * D_;

#define UPDATE(KV, VV)                                                   \
    do {                                                                 \
        float dp = (KV).x * qv.x + (KV).y * qv.y                         \
                 + (KV).z * qv.z + (KV).w * qv.w;                        \
        dp += __shfl_xor(dp, 16);                                        \
        dp += __shfl_xor(dp, 8);                                         \
        dp += __shfl_xor(dp, 4);                                         \
        dp += __shfl_xor(dp, 2);                                         \
        dp += __shfl_xor(dp, 1);                                         \
        const float mn   = fmaxf(m, dp);                                 \
        const float corr = __expf(m - mn);                               \
        const float p    = __expf(dp - mn);                              \
        l   = l   * corr + p;                                            \
        o.x = o.x * corr + p * (VV).x;                                   \
        o.y = o.y * corr + p * (VV).y;                                   \
        o.z = o.z * corr + p * (VV).z;                                   \
        o.w = o.w * corr + p * (VV).w;                                   \
        m = mn;                                                          \
    } while (0)

    if (limit == KPW_) {
        // fast path: full 128-key tile, 2-stage pipelined (2 pairs ahead)
        const float* kp = kbase + (size_t)base * D_ + lane * 4;
        const float* vp = vbase + (size_t)base * D_ + lane * 4;
        f4n ka = ntld4(kp),        va = ntld4(vp);
        f4n kb = ntld4(kp + 256),  vb = ntld4(vp + 256);
        kp += 512; vp += 512;
        for (int i = 0; i < 31; ++i) {
            const f4n kc = ntld4(kp),       vc = ntld4(vp);
            const f4n kd = ntld4(kp + 256), vd = ntld4(vp + 256);
            kp += 512; vp += 512;
            UPDATE(ka, va);
            UPDATE(kb, vb);
            ka = kc; va = vc; kb = kd; vb = vd;
        }
        UPDATE(ka, va);
        UPDATE(kb, vb);
    } else {
        // generic path: paired loop + odd tail (half 0 only)
        const int npairs = limit >> 1;
        for (int i = 0; i < npairs; ++i) {
            const int s0 = base + i * 2;
            const f4n kv = ntld4(kbase + (size_t)s0 * D_ + lane * 4);
            const f4n vv = ntld4(vbase + (size_t)s0 * D_ + lane * 4);
            UPDATE(kv, vv);
        }
        if ((limit & 1) && half == 0) {
            const int s = base + limit - 1;
            const f4n kv = ntld4(kbase + (size_t)s * D_ + li * 4);
            const f4n vv = ntld4(vbase + (size_t)s * D_ + li * 4);
            UPDATE(kv, vv);
        }
    }
#undef UPDATE

    // combine the 8 half-wave partials via LDS -> one partial per block
    __shared__ float s_o[NPART_][D_];
    __shared__ float s_m[NPART_];
    __shared__ float s_l[NPART_];
    const int pi = wave * 2 + half;
    *(f4n*)&s_o[pi][li * 4] = o;
    if (li == 0) { s_m[pi] = m; s_l[pi] = l; }
    __syncthreads();

    if (wave == 0) {
        float M = -INFINITY;
        #pragma unroll
        for (int p = 0; p < NPART_; ++p) M = fmaxf(M, s_m[p]);

        float* pp = part + ((size_t)bh * NSPLIT_ + split) * PSTRIDE_;
        const int d0 = lane * 2;
        if (M == -INFINITY) {
            pp[d0]     = 0.0f;
            pp[d0 + 1] = 0.0f;
            if (lane == 0) { pp[D_] = -INFINITY; pp[D_ + 1] = 0.0f; }
        } else {
            float L = 0.0f, a0 = 0.0f, a1 = 0.0f;
            #pragma unroll
            for (int p = 0; p < NPART_; ++p) {
                const float mp = s_m[p];
                const float w  = (mp == -INFINITY) ? 0.0f : __expf(mp - M);
                L  += w * s_l[p];
                a0 += w * s_o[p][d0];
                a1 += w * s_o[p][d0 + 1];
            }
            pp[d0]     = a0;
            pp[d0 + 1] = a1;
            if (lane == 0) { pp[D_] = M; pp[D_ + 1] = L; }
        }
    }
}

// one wave per bh: merges the 8 split partials plus the new key/value
// (which logically replaces cache row cpos) as a 9th partial (m=sc, l=1).
__global__ __launch_bounds__(64) void attn_combine_kernel(
    const float* __restrict__ q,
    const float* __restrict__ knew,
    const float* __restrict__ vnew,
    const float* __restrict__ part,
    float*       __restrict__ out)
{
    const int bh   = blockIdx.x;   // 0..255
    const int lane = threadIdx.x;  // 0..63
    const float scale = 0.08838834764831845f;

    const float2 qv = *(const float2*)(q    + (size_t)bh * D_ + lane * 2);
    const float2 kn = *(const float2*)(knew + (size_t)bh * D_ + lane * 2);
    float dp = qv.x * kn.x + qv.y * kn.y;
    #pragma unroll
    for (int off = 32; off > 0; off >>= 1) dp += __shfl_xor(dp, off);
    const float sc = dp * scale;

    const float* pb = part + (size_t)bh * NSPLIT_ * PSTRIDE_;

    float M = sc;
    #pragma unroll
    for (int p = 0; p < NSPLIT_; ++p) M = fmaxf(M, pb[p * PSTRIDE_ + D_]);

    const int d0 = lane * 2;
    const float2 vn = *(const float2*)(vnew + (size_t)bh * D_ + d0);
    const float wn = __expf(sc - M);
    float L  = wn;            // new-key partial has l = 1
    float a0 = wn * vn.x;
    float a1 = wn * vn.y;
    #pragma unroll
    for (int p = 0; p < NSPLIT_; ++p) {
        const float mp = pb[p * PSTRIDE_ + D_];
        const float w  = (mp == -INFINITY) ? 0.0f : __expf(mp - M);
        L  += w * pb[p * PSTRIDE_ + D_ + 1];
        a0 += w * pb[p * PSTRIDE_ + d0];
        a1 += w * pb[p * PSTRIDE_ + d0 + 1];
    }
    out[(size_t)bh * D_ + d0]     = a0 / L;
    out[(size_t)bh * D_ + d0 + 1] = a1 / L;
}

extern "C" void kernel_launch(void* const* d_in, const int* in_sizes, int n_in,
                              void* d_out, int out_size, void* d_ws, size_t ws_size,
                              hipStream_t stream) {
    const float* q    = (const float*)d_in[0];
    const float* knew = (const float*)d_in[1];
    const float* vnew = (const float*)d_in[2];
    const float* ck   = (const float*)d_in[3];
    const float* cv   = (const float*)d_in[4];
    const int*   cpos = (const int*)d_in[5];
    float* out  = (float*)d_out;
    float* part = (float*)d_ws;   // needs 256*8*130*4 = 1,064,960 B

    dim3 grid1(BH_, NSPLIT_);
    attn_partial_kernel<<<grid1, 256, 0, stream>>>(q, ck, cv, cpos, part);
    attn_combine_kernel<<<BH_, 64, 0, stream>>>(q, knew, vnew, part, out);
}